// Round 9
// baseline (197.295 us; speedup 1.0000x reference)
//
#include <hip/hip_runtime.h>
#include <cstddef>

#define N_NODES_C 50000
#define N_NODES_PAD 50048
#define N_EDGES_C 800000

typedef _Float16 f16x8 __attribute__((ext_vector_type(8)));
typedef float    f32x4 __attribute__((ext_vector_type(4)));

constexpr int XSTR = 72;           // f16 stride for per-wave h buffer
constexpr int MQ_BLOCKS   = 1563;  // ceil(50000/32) compute blocks (32 nodes)
constexpr int FILL_BLOCKS = 782;   // ceil(800000/1024), 8 edges/thread @128thr
constexpr int DEG_BLOCKS  = 782;   // ceil(800000/1024), 4 edges/thread @256thr

// global -> LDS direct copy, 16B per lane. lds ptr must be wave-uniform base;
// HW writes base + lane*16. global ptr is per-lane.
__device__ __forceinline__ void gll16(const void* g, void* l) {
    __builtin_amdgcn_global_load_lds(
        (const __attribute__((address_space(1))) void*)g,
        (__attribute__((address_space(3))) void*)l, 16, 0, 0);
}

// ---------------------------------------------------------------------------
// prep (wT, W3T swizzled) + deg fused (4 shadow arrays, 4 edges/thread).
//  wT[l][j][k] = W_l[k][j] (f16)                      idx [0, 28672)
//  W3T[r=y*64+x][64 k] (f16), 16B chunks XOR-swizzled: chunk c of row r
//  stored at chunk c^(r&7). Value = w_out[k*2048 + r].
//  Coalesced-read mapping (transpose scatter on the write side).
//  Deg pass captures rank[e] = old count in shadow k = (e>>8)&3 —
//  makes the CSR fill atomic-free (slot = shoff[k][col] + rank[e]).
// ---------------------------------------------------------------------------
__global__ void prep_deg_kernel(const float* __restrict__ w_in,
                                const float* __restrict__ w_mid,
                                const float* __restrict__ w_out,
                                const int* __restrict__ col,
                                _Float16* __restrict__ wT,
                                _Float16* __restrict__ W3T,
                                int* __restrict__ deg4,   // [4][N_NODES_C]
                                int* __restrict__ rank)   // [N_EDGES_C]
{
    const int b = blockIdx.x;
    if (b < 624) {
        const int idx = b * 256 + threadIdx.x;
        if (idx < 7 * 4096) {
            const int l = idx >> 12, rem = idx & 4095;
            const int k = rem >> 6, j = rem & 63;      // lanes: consecutive j
            const float v = (l == 0) ? w_in[k * 64 + j]
                                     : w_mid[(size_t)(l - 1) * 4096 + k * 64 + j];
            wT[(size_t)l * 4096 + j * 64 + k] = (_Float16)v;
        } else {
            const int i2 = idx - 7 * 4096;             // < 131072
            const int k = i2 >> 11, r = i2 & 2047;     // lanes: consecutive r
            const int c = k >> 3;
            const int pos = ((c ^ (r & 7)) << 3) | (k & 7);
            W3T[(size_t)r * 64 + pos] = (_Float16)w_out[(size_t)k * 2048 + r];
        }
    } else {
        const int e0 = (b - 624) * 1024 + threadIdx.x;
        #pragma unroll
        for (int k = 0; k < 4; ++k) {
            const int e = e0 + k * 256;
            if (e < N_EDGES_C)
                rank[e] = atomicAdd(&deg4[k * N_NODES_C + col[e]], 1);
        }
    }
}

// ---------------------------------------------------------------------------
// 3-phase parallel scan; scan3 also emits dinv and per-shadow offsets shoff.
// ---------------------------------------------------------------------------
__global__ void scan1_kernel(const int* __restrict__ deg4, int* __restrict__ bsum)
{
    const int t = threadIdx.x;
    const int i = blockIdx.x * 256 + t;
    int v = 0;
    if (i < N_NODES_C) {
        #pragma unroll
        for (int k = 0; k < 4; ++k) v += deg4[k * N_NODES_C + i];
    }
    #pragma unroll
    for (int d = 1; d < 64; d <<= 1) v += __shfl_xor(v, d);
    __shared__ int s[4];
    if ((t & 63) == 0) s[t >> 6] = v;
    __syncthreads();
    if (t == 0) bsum[blockIdx.x] = s[0] + s[1] + s[2] + s[3];
}

__global__ void scan2_kernel(const int* __restrict__ bsum, int* __restrict__ boff,
                             int* __restrict__ rowptr)
{
    __shared__ int sh[256];
    const int t = threadIdx.x;
    const int v = (t < 196) ? bsum[t] : 0;
    sh[t] = v;
    __syncthreads();
    for (int d = 1; d < 256; d <<= 1) {
        const int u = (t >= d) ? sh[t - d] : 0;
        __syncthreads();
        sh[t] += u;
        __syncthreads();
    }
    if (t < 196) boff[t] = sh[t] - v;     // exclusive
    if (t == 0) rowptr[N_NODES_C] = N_EDGES_C;
}

__global__ void scan3_kernel(const int* __restrict__ deg4, const int* __restrict__ boff,
                             int* __restrict__ rowptr, int* __restrict__ shoff,
                             float* __restrict__ dinv)
{
    const int t = threadIdx.x;
    const int i = blockIdx.x * 256 + t;
    const int lane = t & 63, w = t >> 6;
    int d[4];
    int v = 0;
    if (i < N_NODES_C) {
        #pragma unroll
        for (int k = 0; k < 4; ++k) { d[k] = deg4[k * N_NODES_C + i]; v += d[k]; }
    } else {
        d[0] = d[1] = d[2] = d[3] = 0;
    }
    int inc = v;
    #pragma unroll
    for (int dd = 1; dd < 64; dd <<= 1) {
        const int u = __shfl_up(inc, dd);
        if (lane >= dd) inc += u;
    }
    __shared__ int ws[4];
    if (lane == 63) ws[w] = inc;
    __syncthreads();
    int wo = 0;
    #pragma unroll
    for (int k = 0; k < 4; ++k) if (k < w) wo += ws[k];
    const int excl = boff[blockIdx.x] + wo + inc - v;
    if (i < N_NODES_C) {
        rowptr[i] = excl;
        dinv[i] = (v > 0) ? rsqrtf((float)v) : 0.f;
        int o = excl;
        shoff[0 * N_NODES_C + i] = o; o += d[0];
        shoff[1 * N_NODES_C + i] = o; o += d[1];
        shoff[2 * N_NODES_C + i] = o; o += d[2];
        shoff[3 * N_NODES_C + i] = o;
    }
}

// ---------------------------------------------------------------------------
// MEGA kernel (128 threads = 2 waves): compute blocks first, fill after.
//  Compute blocks: 32 nodes, 2 waves, 40 KB LDS -> 4 blocks/CU (vs R8's 2).
//   Phase 1: per-wave MLP, 16 nodes/wave.
//   Phase 2: slice-per-wave (wave w owns y = 2*yy + w, 16 slices, computes
//   all 32 nodes/slice; A-read feeds 2 MFMAs). Wave-private 2-slot LDS ring
//   fed by global_load_lds; ZERO barriers in loop; counted vmcnt ledger
//   (verified in R8): prologue bout(4)+s0(8)+s1(8); vmcnt(16)+barrier for
//   bout; loop wait 8/9/1 at yy=0/mid/15; store always issued; refill after
//   lgkmcnt(0).
// ---------------------------------------------------------------------------
__launch_bounds__(128, 2)
__global__ void mega_kernel(const float* __restrict__ xf,
                            const float* __restrict__ b_in,
                            const float* __restrict__ b_mid,
                            const _Float16* __restrict__ wT,
                            const _Float16* __restrict__ W3T,
                            const float* __restrict__ b_out,
                            const float* __restrict__ dinv,
                            float* __restrict__ qs,
                            const int* __restrict__ row,
                            const int* __restrict__ col,
                            const int* __restrict__ shoff,
                            const int* __restrict__ rank,
                            int* __restrict__ src)
{
    // f16[0,4096)  = b_out f32 8KB overlay; hball (2x1152 f16) lives in its
    //                first 4608 B during phase 1 (dead before overlay use).
    // f16[4096, 4096+2*8192) = per-wave 2-slot slice rings (16 KB each).
    __shared__ _Float16 smem[20480];   // 40960 B -> 4 blocks/CU

    if (blockIdx.x >= MQ_BLOCKS) {
        // ---------------- fill part (no atomics), 8 edges/thread ----------
        const int base = (blockIdx.x - MQ_BLOCKS) * 1024 + threadIdx.x;
        #pragma unroll
        for (int u = 0; u < 8; ++u) {
            const int e = base + u * 128;
            if (e < N_EDGES_C) {
                const int c = col[e];
                const int kk = (e >> 8) & 3;
                const int slot = shoff[kk * N_NODES_C + c] + rank[e];
                src[slot] = row[e];
            }
        }
        return;
    }

    const int t    = threadIdx.x;
    const int w    = t >> 6;           // 0..1
    const int lane = t & 63;
    const int quad = lane >> 4;
    const int lrow = lane & 15;
    const int node0 = blockIdx.x * 32 + w * 16;
    _Float16* hb = &smem[w * 1152];    // 16*72 f16 per wave

    // ---- phase 1a: stage x -> f16 hb ----
    {
        const int n = min(node0 + lrow, N_NODES_C - 1);
        const float4* src4 = (const float4*)(xf + (size_t)n * 64 + quad * 16);
        _Float16 tmp[16];
        #pragma unroll
        for (int i = 0; i < 4; ++i) {
            const float4 v = src4[i];
            tmp[i * 4 + 0] = (_Float16)v.x;
            tmp[i * 4 + 1] = (_Float16)v.y;
            tmp[i * 4 + 2] = (_Float16)v.z;
            tmp[i * 4 + 3] = (_Float16)v.w;
        }
        *(f16x8*)&hb[lrow * XSTR + quad * 16]     = *(f16x8*)&tmp[0];
        *(f16x8*)&hb[lrow * XSTR + quad * 16 + 8] = *(f16x8*)&tmp[8];
    }

    // ---- phase 1b: 7 layers, wave-private, 16 nodes/wave ----
    {
        const _Float16* wTl = wT;
        const float* bsrc = b_in;
        for (int l = 0; l < 7; ++l) {
            const f16x8 A0 = *(const f16x8*)&hb[lrow * XSTR + quad * 8];
            const f16x8 A1 = *(const f16x8*)&hb[lrow * XSTR + 32 + quad * 8];
            #pragma unroll
            for (int Nt = 0; Nt < 4; ++Nt) {
                const f16x8 B0 = *(const f16x8*)(wTl + (Nt * 16 + lrow) * 64 + quad * 8);
                const f16x8 B1 = *(const f16x8*)(wTl + (Nt * 16 + lrow) * 64 + 32 + quad * 8);
                const float bias = bsrc[Nt * 16 + lrow];
                f32x4 C = {0.f, 0.f, 0.f, 0.f};
                C = __builtin_amdgcn_mfma_f32_16x16x32_f16(A0, B0, C, 0, 0, 0);
                C = __builtin_amdgcn_mfma_f32_16x16x32_f16(A1, B1, C, 0, 0, 0);
                #pragma unroll
                for (int r = 0; r < 4; ++r) {
                    const float v = fmaxf(C[r] + bias, 0.f);
                    hb[(quad * 4 + r) * XSTR + Nt * 16 + lrow] = (_Float16)v;
                }
            }
            wTl += 4096;
            bsrc = b_mid + (size_t)l * 64;
        }
    }

    // sync1: all hball written (cross-wave reads next)
    __syncthreads();

    // ---- phase 2 setup: h B-frags for BOTH node groups + x + dinv ----
    f16x8 Bh[2][2];
    #pragma unroll
    for (int g = 0; g < 2; ++g)
        #pragma unroll
        for (int ks = 0; ks < 2; ++ks)
            Bh[g][ks] = *(const f16x8*)&smem[g * 1152 + lrow * XSTR + ks * 32 + quad * 8];

    float4 xc[2][4];
    #pragma unroll
    for (int g = 0; g < 2; ++g) {
        const int na = min(blockIdx.x * 32 + g * 16 + lrow, N_NODES_C - 1);
        #pragma unroll
        for (int xt = 0; xt < 4; ++xt)
            xc[g][xt] = *(const float4*)(xf + (size_t)na * 64 + xt * 16 + quad * 4);
    }
    const int nodeS = blockIdx.x * 32 + (lane & 31);    // store node (quad<2 lanes)
    const float dsel = dinv[min(nodeS, N_NODES_C - 1)];

    // sync2: drains all lgkm/vm; hball now dead -> b_out overlay legal
    __syncthreads();

    // ---- prologue staging: bout (cooperative, 4 gll/wave) + own slices ----
    {
        float* lb = (float*)smem;
        #pragma unroll
        for (int s = 0; s < 4; ++s)
            gll16(b_out + (size_t)(w * 1024 + s * 256 + lane * 4),
                  lb + w * 1024 + s * 256);
        __builtin_amdgcn_sched_barrier(0);
        _Float16* ringp = &smem[4096 + w * 8192];
        #pragma unroll
        for (int s = 0; s < 2; ++s) {
            const int y = s * 2 + w;
            #pragma unroll
            for (int g8 = 0; g8 < 8; ++g8)
                gll16(W3T + (size_t)y * 4096 + g8 * 512 + (size_t)lane * 8,
                      ringp + s * 4096 + g8 * 512);
        }
        __builtin_amdgcn_sched_barrier(0);
    }
    asm volatile("s_waitcnt vmcnt(16)" ::: "memory");   // own bout landed
    __builtin_amdgcn_s_barrier();                       // bout visible to both waves
    __builtin_amdgcn_sched_barrier(0);

    const int swz = lrow & 7;
    const int cp0 = ((quad)     ^ swz) * 8;   // ks=0 chunk offset (f16)
    const int cp1 = ((4 + quad) ^ swz) * 8;   // ks=1 chunk offset
    const float* lbf = (const float*)smem;    // staged b_out (f32)
    _Float16* ring = &smem[4096 + w * 8192];

    // ---- phase 2: 16 slices/wave, wave-private ring, zero barriers ----
    #pragma unroll
    for (int yy = 0; yy < 16; ++yy) {
        if (yy == 0)       asm volatile("s_waitcnt vmcnt(8)" ::: "memory");
        else if (yy == 15) asm volatile("s_waitcnt vmcnt(1)" ::: "memory");
        else               asm volatile("s_waitcnt vmcnt(9)" ::: "memory");
        __builtin_amdgcn_sched_barrier(0);

        const int y = yy * 2 + w;
        const _Float16* cur = ring + (yy & 1) * 4096;
        float q0 = 0.f, q1 = 0.f;
        #pragma unroll
        for (int xt = 0; xt < 4; ++xt) {
            const _Float16* rp = cur + (xt * 16 + lrow) * 64;
            const f16x8 A0 = *(const f16x8*)(rp + cp0);
            const f16x8 A1 = *(const f16x8*)(rp + cp1);
            f32x4 C0 = {0.f,0.f,0.f,0.f}, C1 = {0.f,0.f,0.f,0.f};
            C0 = __builtin_amdgcn_mfma_f32_16x16x32_f16(A0, Bh[0][0], C0, 0, 0, 0);
            C0 = __builtin_amdgcn_mfma_f32_16x16x32_f16(A1, Bh[0][1], C0, 0, 0, 0);
            C1 = __builtin_amdgcn_mfma_f32_16x16x32_f16(A0, Bh[1][0], C1, 0, 0, 0);
            C1 = __builtin_amdgcn_mfma_f32_16x16x32_f16(A1, Bh[1][1], C1, 0, 0, 0);

            const float4 bf = *(const float4*)(lbf + y * 64 + xt * 16 + quad * 4);
            q0 += (C0[0] + bf.x) * xc[0][xt].x + (C0[1] + bf.y) * xc[0][xt].y
                + (C0[2] + bf.z) * xc[0][xt].z + (C0[3] + bf.w) * xc[0][xt].w;
            q1 += (C1[0] + bf.x) * xc[1][xt].x + (C1[1] + bf.y) * xc[1][xt].y
                + (C1[2] + bf.z) * xc[1][xt].z + (C1[3] + bf.w) * xc[1][xt].w;
        }
        q0 += __shfl_xor(q0, 16); q0 += __shfl_xor(q0, 32);
        q1 += __shfl_xor(q1, 16); q1 += __shfl_xor(q1, 32);

        // lanes with quad 0/1 store q0/q1 for nodes blk*32 + lane(0..31)
        const float qv = (quad == 0) ? q0 : q1;
        if (quad < 2)
            qs[(size_t)nodeS * 32 + y] = qv * dsel;     // 1 store instr/wave

        __builtin_amdgcn_sched_barrier(0);
        if (yy + 2 < 16) {                              // refill just-consumed slot
            const int yn = (yy + 2) * 2 + w;
            _Float16* dst = ring + (yy & 1) * 4096;
            asm volatile("s_waitcnt lgkmcnt(0)" ::: "memory");  // slot reads drained
            __builtin_amdgcn_sched_barrier(0);
            #pragma unroll
            for (int g8 = 0; g8 < 8; ++g8)
                gll16(W3T + (size_t)yn * 4096 + g8 * 512 + (size_t)lane * 8,
                      dst + g8 * 512);
        }
        __builtin_amdgcn_sched_barrier(0);
    }
}

// ---------------------------------------------------------------------------
// Gather: out[n,y] = dinv[n] * sum_{s in CSR row n} qs[src[s], y]
// 8 threads/node, float4 per thread (32 nodes per 256-thread block).
// ---------------------------------------------------------------------------
__global__ void gather_kernel(const int* __restrict__ rowptr, const int* __restrict__ src,
                              const float* __restrict__ qs, const float* __restrict__ dinv,
                              float* __restrict__ out)
{
    const int t = threadIdx.x;
    const int node = blockIdx.x * 32 + (t >> 3);
    if (node >= N_NODES_C) return;
    const int yq = (t & 7) * 4;
    const int s0 = rowptr[node];
    const int s1 = rowptr[node + 1];
    float4 acc = {0.f, 0.f, 0.f, 0.f};
    int s = s0;
    for (; s + 4 <= s1; s += 4) {
        const int r0 = src[s], r1 = src[s + 1], r2 = src[s + 2], r3 = src[s + 3];
        const float4 a0 = *(const float4*)(qs + (size_t)r0 * 32 + yq);
        const float4 a1 = *(const float4*)(qs + (size_t)r1 * 32 + yq);
        const float4 a2 = *(const float4*)(qs + (size_t)r2 * 32 + yq);
        const float4 a3 = *(const float4*)(qs + (size_t)r3 * 32 + yq);
        acc.x += a0.x + a1.x + a2.x + a3.x;
        acc.y += a0.y + a1.y + a2.y + a3.y;
        acc.z += a0.z + a1.z + a2.z + a3.z;
        acc.w += a0.w + a1.w + a2.w + a3.w;
    }
    for (; s < s1; ++s) {
        const float4 a = *(const float4*)(qs + (size_t)src[s] * 32 + yq);
        acc.x += a.x; acc.y += a.y; acc.z += a.z; acc.w += a.w;
    }
    const float dv = dinv[node];
    float4 r;
    r.x = acc.x * dv; r.y = acc.y * dv; r.z = acc.z * dv; r.w = acc.w * dv;
    *(float4*)(out + (size_t)node * 32 + yq) = r;
}

// ---------------------------------------------------------------------------
extern "C" void kernel_launch(void* const* d_in, const int* in_sizes, int n_in,
                              void* d_out, int out_size, void* d_ws, size_t ws_size,
                              hipStream_t stream)
{
    const float* xf    = (const float*)d_in[0];
    const int*   eidx  = (const int*)d_in[1];
    const float* w_in  = (const float*)d_in[2];
    const float* b_in  = (const float*)d_in[3];
    const float* w_mid = (const float*)d_in[4];
    const float* b_mid = (const float*)d_in[5];
    const float* w_out = (const float*)d_in[6];
    const float* b_out = (const float*)d_in[7];
    float* out = (float*)d_out;

    const int* row = eidx;
    const int* col = eidx + N_EDGES_C;

    // workspace layout (bytes)
    char* ws = (char*)d_ws;
    float*    qs     = (float*)(ws + 0);             //  6,406,144 (50048 rows)
    int*      deg4   = (int*)(ws + 6406144);         //    800,000 (4 shadows)
    float*    dinv   = (float*)(ws + 7206144);       //    200,000
    _Float16* wT     = (_Float16*)(ws + 7406144);    //     57,344
    _Float16* W3T    = (_Float16*)(ws + 7463488);    //    262,144
    int*      rowptr = (int*)(ws + 7725632);         //    200,004
    int*      shoff  = (int*)(ws + 7925636);         //    800,000 (4 shadows)
    int*      rank   = (int*)(ws + 8725636);         //  3,200,000
    int*      srcb   = (int*)(ws + 11925636);        //  3,200,000
    int*      bsum   = (int*)(ws + 15125636);        //        784
    int*      boff   = (int*)(ws + 15126420);        //        784

    hipMemsetAsync(deg4, 0, 4 * N_NODES_C * sizeof(int), stream);

    prep_deg_kernel<<<dim3(624 + DEG_BLOCKS), dim3(256), 0, stream>>>(
        w_in, w_mid, w_out, col, wT, W3T, deg4, rank);

    scan1_kernel<<<dim3(196), dim3(256), 0, stream>>>(deg4, bsum);
    scan2_kernel<<<dim3(1), dim3(256), 0, stream>>>(bsum, boff, rowptr);
    scan3_kernel<<<dim3(196), dim3(256), 0, stream>>>(deg4, boff, rowptr, shoff, dinv);

    mega_kernel<<<dim3(MQ_BLOCKS + FILL_BLOCKS), dim3(128), 0, stream>>>(
        xf, b_in, b_mid, wT, W3T, b_out, dinv, qs, row, col, shoff, rank, srcb);

    gather_kernel<<<dim3(1563), dim3(256), 0, stream>>>(rowptr, srcb, qs, dinv, out);
}

// Round 10
// 191.203 us; speedup vs baseline: 1.0319x; 1.0319x over previous
//
#include <hip/hip_runtime.h>
#include <cstddef>

#define N_NODES_C 50000
#define N_NODES_PAD 50048
#define N_EDGES_C 800000

typedef _Float16 f16x8 __attribute__((ext_vector_type(8)));
typedef float    f32x4 __attribute__((ext_vector_type(4)));

constexpr int XSTR = 72;           // f16 stride for per-wave h buffer
constexpr int MQ_BLOCKS   = 782;   // ceil(50000/64) compute blocks
constexpr int FILL_BLOCKS = 782;   // ceil(800000/1024), 4 edges/thread
constexpr int DEG_BLOCKS  = 782;   // ceil(800000/1024), 4 edges/thread

// global -> LDS direct copy, 16B per lane. lds ptr must be wave-uniform base;
// HW writes base + lane*16. global ptr is per-lane.
__device__ __forceinline__ void gll16(const void* g, void* l) {
    __builtin_amdgcn_global_load_lds(
        (const __attribute__((address_space(1))) void*)g,
        (__attribute__((address_space(3))) void*)l, 16, 0, 0);
}

// ---------------------------------------------------------------------------
// prep (wT, W3T swizzled) + deg fused (4 shadow arrays, 4 edges/thread).
//  wT[l][j][k] = W_l[k][j] (f16)                      idx [0, 28672)
//  W3T[r=y*64+x][64 k] (f16), 16B chunks XOR-swizzled: chunk c of row r
//  stored at chunk c^(r&7). Value = w_out[k*2048 + r].
//  Coalesced-read mapping (transpose scatter on the write side).
//  Deg pass captures rank[e] = old count in shadow k = (e>>8)&3 —
//  makes the CSR fill atomic-free (slot = shoff[k][col] + rank[e]).
// ---------------------------------------------------------------------------
__global__ void prep_deg_kernel(const float* __restrict__ w_in,
                                const float* __restrict__ w_mid,
                                const float* __restrict__ w_out,
                                const int* __restrict__ col,
                                _Float16* __restrict__ wT,
                                _Float16* __restrict__ W3T,
                                int* __restrict__ deg4,   // [4][N_NODES_C]
                                int* __restrict__ rank)   // [N_EDGES_C]
{
    const int b = blockIdx.x;
    if (b < 624) {
        const int idx = b * 256 + threadIdx.x;
        if (idx < 7 * 4096) {
            const int l = idx >> 12, rem = idx & 4095;
            const int k = rem >> 6, j = rem & 63;      // lanes: consecutive j
            const float v = (l == 0) ? w_in[k * 64 + j]
                                     : w_mid[(size_t)(l - 1) * 4096 + k * 64 + j];
            wT[(size_t)l * 4096 + j * 64 + k] = (_Float16)v;
        } else {
            const int i2 = idx - 7 * 4096;             // < 131072
            const int k = i2 >> 11, r = i2 & 2047;     // lanes: consecutive r
            const int c = k >> 3;
            const int pos = ((c ^ (r & 7)) << 3) | (k & 7);
            W3T[(size_t)r * 64 + pos] = (_Float16)w_out[(size_t)k * 2048 + r];
        }
    } else {
        const int e0 = (b - 624) * 1024 + threadIdx.x;
        #pragma unroll
        for (int k = 0; k < 4; ++k) {
            const int e = e0 + k * 256;
            if (e < N_EDGES_C)
                rank[e] = atomicAdd(&deg4[k * N_NODES_C + col[e]], 1);
        }
    }
}

// ---------------------------------------------------------------------------
// scan1: per-256-node block sums of deg (4 shadows).
// ---------------------------------------------------------------------------
__global__ void scan1_kernel(const int* __restrict__ deg4, int* __restrict__ bsum)
{
    const int t = threadIdx.x;
    const int i = blockIdx.x * 256 + t;
    int v = 0;
    if (i < N_NODES_C) {
        #pragma unroll
        for (int k = 0; k < 4; ++k) v += deg4[k * N_NODES_C + i];
    }
    #pragma unroll
    for (int d = 1; d < 64; d <<= 1) v += __shfl_xor(v, d);
    __shared__ int s[4];
    if ((t & 63) == 0) s[t >> 6] = v;
    __syncthreads();
    if (t == 0) bsum[blockIdx.x] = s[0] + s[1] + s[2] + s[3];
}

// ---------------------------------------------------------------------------
// scan3 (absorbs old scan2): each block locally scans bsum[196] for its own
// exclusive offset, then emits rowptr, dinv, and per-shadow offsets shoff.
// ---------------------------------------------------------------------------
__global__ void scan3_kernel(const int* __restrict__ deg4, const int* __restrict__ bsum,
                             int* __restrict__ rowptr, int* __restrict__ shoff,
                             float* __restrict__ dinv)
{
    __shared__ int sincl[256];
    const int t = threadIdx.x;
    const int bv = (t < 196) ? bsum[t] : 0;
    sincl[t] = bv;
    __syncthreads();
    for (int d = 1; d < 256; d <<= 1) {
        const int u = (t >= d) ? sincl[t - d] : 0;
        __syncthreads();
        sincl[t] += u;
        __syncthreads();
    }
    __shared__ int sboff;
    if (t == 0) {
        const int b = blockIdx.x;
        sboff = sincl[b] - bsum[b];                    // exclusive block offset
        if (b == 0) rowptr[N_NODES_C] = N_EDGES_C;
    }
    __syncthreads();

    const int i = blockIdx.x * 256 + t;
    const int lane = t & 63, w = t >> 6;
    int d4[4];
    int v = 0;
    if (i < N_NODES_C) {
        #pragma unroll
        for (int k = 0; k < 4; ++k) { d4[k] = deg4[k * N_NODES_C + i]; v += d4[k]; }
    } else {
        d4[0] = d4[1] = d4[2] = d4[3] = 0;
    }
    int inc = v;
    #pragma unroll
    for (int dd = 1; dd < 64; dd <<= 1) {
        const int u = __shfl_up(inc, dd);
        if (lane >= dd) inc += u;
    }
    __shared__ int ws[4];
    if (lane == 63) ws[w] = inc;
    __syncthreads();
    int wo = 0;
    #pragma unroll
    for (int k = 0; k < 4; ++k) if (k < w) wo += ws[k];
    const int excl = sboff + wo + inc - v;
    if (i < N_NODES_C) {
        rowptr[i] = excl;
        dinv[i] = (v > 0) ? rsqrtf((float)v) : 0.f;
        int o = excl;
        shoff[0 * N_NODES_C + i] = o; o += d4[0];
        shoff[1 * N_NODES_C + i] = o; o += d4[1];
        shoff[2 * N_NODES_C + i] = o; o += d4[2];
        shoff[3 * N_NODES_C + i] = o;
    }
}

// ---------------------------------------------------------------------------
// MEGA kernel (R7-exact, best-measured): compute blocks first, fill after.
//  Compute blocks: 64 nodes, 4 waves x 16 nodes.
//   Phase 1: per-wave MLP (wave-private hb LDS region, zero barriers).
//   Phase 2: counted-vmcnt pipeline: 3-slice LDS ring fed by global_load_lds,
//   raw s_barrier + counted s_waitcnt vmcnt (2/3 prologue, 4 steady).
// ---------------------------------------------------------------------------
__launch_bounds__(256, 4)
__global__ void mega_kernel(const float* __restrict__ xf,
                            const float* __restrict__ b_in,
                            const float* __restrict__ b_mid,
                            const _Float16* __restrict__ wT,
                            const _Float16* __restrict__ W3T,
                            const float* __restrict__ b_out,
                            const float* __restrict__ dinv,
                            float* __restrict__ qs,
                            const int* __restrict__ row,
                            const int* __restrict__ col,
                            const int* __restrict__ shoff,
                            const int* __restrict__ rank,
                            int* __restrict__ src)
{
    // 33792 B total: f16[0,4608) = hball (phase1) / b_out f32 (phase2);
    //                f16[4608,16896) = 3 x 4096 f16 slice ring.
    __shared__ _Float16 smem[16896];

    if (blockIdx.x >= MQ_BLOCKS) {
        // ---------------- fill part (no atomics) ----------------
        const int base = (blockIdx.x - MQ_BLOCKS) * 1024 + threadIdx.x;
        #pragma unroll
        for (int u = 0; u < 4; ++u) {
            const int e = base + u * 256;
            if (e < N_EDGES_C) {
                const int c = col[e];
                const int kk = (e >> 8) & 3;
                const int slot = shoff[kk * N_NODES_C + c] + rank[e];
                src[slot] = row[e];
            }
        }
        return;
    }

    const int t    = threadIdx.x;
    const int w    = t >> 6;
    const int lane = t & 63;
    const int quad = lane >> 4;
    const int lrow = lane & 15;
    const int node0 = blockIdx.x * 64 + w * 16;
    _Float16* hb = &smem[w * 16 * XSTR];

    // ---- phase 1a: stage x -> f16 hb ----
    {
        const int n = min(node0 + lrow, N_NODES_C - 1);
        const float4* src4 = (const float4*)(xf + (size_t)n * 64 + quad * 16);
        _Float16 tmp[16];
        #pragma unroll
        for (int i = 0; i < 4; ++i) {
            const float4 v = src4[i];
            tmp[i * 4 + 0] = (_Float16)v.x;
            tmp[i * 4 + 1] = (_Float16)v.y;
            tmp[i * 4 + 2] = (_Float16)v.z;
            tmp[i * 4 + 3] = (_Float16)v.w;
        }
        *(f16x8*)&hb[lrow * XSTR + quad * 16]     = *(f16x8*)&tmp[0];
        *(f16x8*)&hb[lrow * XSTR + quad * 16 + 8] = *(f16x8*)&tmp[8];
    }

    // ---- phase 1b: 7 layers, wave-private, 16 nodes/wave ----
    {
        const _Float16* wTl = wT;
        const float* bsrc = b_in;
        for (int l = 0; l < 7; ++l) {
            const f16x8 A0 = *(const f16x8*)&hb[lrow * XSTR + quad * 8];
            const f16x8 A1 = *(const f16x8*)&hb[lrow * XSTR + 32 + quad * 8];
            #pragma unroll
            for (int Nt = 0; Nt < 4; ++Nt) {
                const f16x8 B0 = *(const f16x8*)(wTl + (Nt * 16 + lrow) * 64 + quad * 8);
                const f16x8 B1 = *(const f16x8*)(wTl + (Nt * 16 + lrow) * 64 + 32 + quad * 8);
                const float bias = bsrc[Nt * 16 + lrow];
                f32x4 C = {0.f, 0.f, 0.f, 0.f};
                C = __builtin_amdgcn_mfma_f32_16x16x32_f16(A0, B0, C, 0, 0, 0);
                C = __builtin_amdgcn_mfma_f32_16x16x32_f16(A1, B1, C, 0, 0, 0);
                #pragma unroll
                for (int r = 0; r < 4; ++r) {
                    const float v = fmaxf(C[r] + bias, 0.f);
                    hb[(quad * 4 + r) * XSTR + Nt * 16 + lrow] = (_Float16)v;
                }
            }
            wTl += 4096;
            bsrc = b_mid + (size_t)l * 64;
        }
    }

    // ---- phase 2 setup: B-frags (h) from wave-private LDS ----
    const int ra = node0 + lrow;                 // < N_NODES_PAD always
    const int na = min(ra, N_NODES_C - 1);

    f16x8 Bha[2];
    #pragma unroll
    for (int ks = 0; ks < 2; ++ks)
        Bha[ks] = *(const f16x8*)&hb[lrow * XSTR + ks * 32 + quad * 8];
    float4 xca[4];
    #pragma unroll
    for (int xt = 0; xt < 4; ++xt)
        xca[xt] = *(const float4*)(xf + (size_t)na * 64 + xt * 16 + quad * 4);
    const float dva = dinv[na];

    // hball dead from here; __syncthreads drains vmcnt to 0 (clean ledger).
    __syncthreads();

    // ---- prologue: stage b_out (f32, 8KB) over hball region; slices 0,1 ----
    {
        float* lb = (float*)smem;                         // f32 view of [0,8192)B
        const float* gb = b_out + (size_t)(w * 64 + lane) * 4;
        gll16(gb,        lb + w * 256);                   // bytes [0,4096)
        gll16(gb + 1024, lb + 1024 + w * 256);            // bytes [4096,8192)
        #pragma unroll
        for (int s = 0; s < 2; ++s) {
            _Float16* ld = &smem[4608 + s * 4096 + w * 512];
            const _Float16* gs = W3T + (size_t)s * 4096 + (size_t)(w * 64 + lane) * 8;
            gll16(gs,        ld);                         // slice bytes [0,4096)
            gll16(gs + 2048, ld + 2048);                  // slice bytes [4096,8192)
        }
    }

    const int swz = lrow & 7;
    const int cp0 = ((quad)     ^ swz) * 8;   // ks=0 chunk offset (f16)
    const int cp1 = ((4 + quad) ^ swz) * 8;   // ks=1 chunk offset
    const float* lbf = (const float*)smem;    // staged b_out

    // ---- phase 2: counted-vmcnt 3-slice ring, one raw barrier per y ----
    int rcur = 0;                              // y % 3
    for (int y = 0; y < 32; ++y) {
        if (y == 0)      asm volatile("s_waitcnt vmcnt(2)" ::: "memory");
        else if (y == 1) asm volatile("s_waitcnt vmcnt(3)" ::: "memory");
        else             asm volatile("s_waitcnt vmcnt(4)" ::: "memory");
        __builtin_amdgcn_s_barrier();
        __builtin_amdgcn_sched_barrier(0);

        // issue slice (y+2)&31 into ring[(y+2)%3] (= ring[(y-1)%3], retired)
        {
            const int ys = (y + 2) & 31;
            const int ri = (rcur == 0) ? 2 : rcur - 1;
            _Float16* ld = &smem[4608 + ri * 4096 + w * 512];
            const _Float16* gs = W3T + (size_t)ys * 4096 + (size_t)(w * 64 + lane) * 8;
            gll16(gs,        ld);
            gll16(gs + 2048, ld + 2048);
        }

        const _Float16* cur = &smem[4608 + rcur * 4096];
        float qa = 0.f;
        #pragma unroll
        for (int xt = 0; xt < 4; ++xt) {
            const _Float16* rp = cur + (xt * 16 + lrow) * 64;
            const f16x8 A0 = *(const f16x8*)(rp + cp0);
            const f16x8 A1 = *(const f16x8*)(rp + cp1);
            f32x4 Ca = {0.f, 0.f, 0.f, 0.f};
            Ca = __builtin_amdgcn_mfma_f32_16x16x32_f16(A0, Bha[0], Ca, 0, 0, 0);
            Ca = __builtin_amdgcn_mfma_f32_16x16x32_f16(A1, Bha[1], Ca, 0, 0, 0);

            const float4 bf = *(const float4*)(lbf + y * 64 + xt * 16 + quad * 4);
            qa += (Ca[0] + bf.x) * xca[xt].x + (Ca[1] + bf.y) * xca[xt].y
                + (Ca[2] + bf.z) * xca[xt].z + (Ca[3] + bf.w) * xca[xt].w;
        }
        qa += __shfl_xor(qa, 16);
        qa += __shfl_xor(qa, 32);

        if (quad == (y >> 3)) {               // 16 lanes/wave always -> exec!=0
            qs[(size_t)ra * 32 + y] = qa * dva;   // qs padded to 50048 rows
        }

        rcur = (rcur == 2) ? 0 : rcur + 1;
    }
}

// ---------------------------------------------------------------------------
// Gather: out[n,y] = dinv[n] * sum_{s in CSR row n} qs[src[s], y]
// 4 threads/node, 8 y's each (two float4 acc); 64 nodes per 256-thread block.
// Halves src-load redundancy vs 8thr/node and doubles qs loads in flight.
// ---------------------------------------------------------------------------
__global__ void gather_kernel(const int* __restrict__ rowptr, const int* __restrict__ src,
                              const float* __restrict__ qs, const float* __restrict__ dinv,
                              float* __restrict__ out)
{
    const int t = threadIdx.x;
    const int node = blockIdx.x * 64 + (t >> 2);
    if (node >= N_NODES_C) return;
    const int yq = (t & 3) * 8;
    const int s0 = rowptr[node];
    const int s1 = rowptr[node + 1];
    float4 accA = {0.f, 0.f, 0.f, 0.f};
    float4 accB = {0.f, 0.f, 0.f, 0.f};
    int s = s0;
    for (; s + 4 <= s1; s += 4) {
        const int r0 = src[s], r1 = src[s + 1], r2 = src[s + 2], r3 = src[s + 3];
        const float4* p0 = (const float4*)(qs + (size_t)r0 * 32 + yq);
        const float4* p1 = (const float4*)(qs + (size_t)r1 * 32 + yq);
        const float4* p2 = (const float4*)(qs + (size_t)r2 * 32 + yq);
        const float4* p3 = (const float4*)(qs + (size_t)r3 * 32 + yq);
        const float4 a0A = p0[0], a0B = p0[1];
        const float4 a1A = p1[0], a1B = p1[1];
        const float4 a2A = p2[0], a2B = p2[1];
        const float4 a3A = p3[0], a3B = p3[1];
        accA.x += a0A.x + a1A.x + a2A.x + a3A.x;
        accA.y += a0A.y + a1A.y + a2A.y + a3A.y;
        accA.z += a0A.z + a1A.z + a2A.z + a3A.z;
        accA.w += a0A.w + a1A.w + a2A.w + a3A.w;
        accB.x += a0B.x + a1B.x + a2B.x + a3B.x;
        accB.y += a0B.y + a1B.y + a2B.y + a3B.y;
        accB.z += a0B.z + a1B.z + a2B.z + a3B.z;
        accB.w += a0B.w + a1B.w + a2B.w + a3B.w;
    }
    for (; s < s1; ++s) {
        const float4* p = (const float4*)(qs + (size_t)src[s] * 32 + yq);
        const float4 aA = p[0], aB = p[1];
        accA.x += aA.x; accA.y += aA.y; accA.z += aA.z; accA.w += aA.w;
        accB.x += aB.x; accB.y += aB.y; accB.z += aB.z; accB.w += aB.w;
    }
    const float dv = dinv[node];
    float4 rA, rB;
    rA.x = accA.x * dv; rA.y = accA.y * dv; rA.z = accA.z * dv; rA.w = accA.w * dv;
    rB.x = accB.x * dv; rB.y = accB.y * dv; rB.z = accB.z * dv; rB.w = accB.w * dv;
    *(float4*)(out + (size_t)node * 32 + yq)     = rA;
    *(float4*)(out + (size_t)node * 32 + yq + 4) = rB;
}

// ---------------------------------------------------------------------------
extern "C" void kernel_launch(void* const* d_in, const int* in_sizes, int n_in,
                              void* d_out, int out_size, void* d_ws, size_t ws_size,
                              hipStream_t stream)
{
    const float* xf    = (const float*)d_in[0];
    const int*   eidx  = (const int*)d_in[1];
    const float* w_in  = (const float*)d_in[2];
    const float* b_in  = (const float*)d_in[3];
    const float* w_mid = (const float*)d_in[4];
    const float* b_mid = (const float*)d_in[5];
    const float* w_out = (const float*)d_in[6];
    const float* b_out = (const float*)d_in[7];
    float* out = (float*)d_out;

    const int* row = eidx;
    const int* col = eidx + N_EDGES_C;

    // workspace layout (bytes)
    char* ws = (char*)d_ws;
    float*    qs     = (float*)(ws + 0);             //  6,406,144 (50048 rows)
    int*      deg4   = (int*)(ws + 6406144);         //    800,000 (4 shadows)
    float*    dinv   = (float*)(ws + 7206144);       //    200,000
    _Float16* wT     = (_Float16*)(ws + 7406144);    //     57,344
    _Float16* W3T    = (_Float16*)(ws + 7463488);    //    262,144
    int*      rowptr = (int*)(ws + 7725632);         //    200,004
    int*      shoff  = (int*)(ws + 7925636);         //    800,000 (4 shadows)
    int*      rank   = (int*)(ws + 8725636);         //  3,200,000
    int*      srcb   = (int*)(ws + 11925636);        //  3,200,000
    int*      bsum   = (int*)(ws + 15125636);        //        784

    hipMemsetAsync(deg4, 0, 4 * N_NODES_C * sizeof(int), stream);

    prep_deg_kernel<<<dim3(624 + DEG_BLOCKS), dim3(256), 0, stream>>>(
        w_in, w_mid, w_out, col, wT, W3T, deg4, rank);

    scan1_kernel<<<dim3(196), dim3(256), 0, stream>>>(deg4, bsum);
    scan3_kernel<<<dim3(196), dim3(256), 0, stream>>>(deg4, bsum, rowptr, shoff, dinv);

    mega_kernel<<<dim3(MQ_BLOCKS + FILL_BLOCKS), dim3(256), 0, stream>>>(
        xf, b_in, b_mid, wT, W3T, b_out, dinv, qs, row, col, shoff, rank, srcb);

    gather_kernel<<<dim3(782), dim3(256), 0, stream>>>(rowptr, srcb, qs, dinv, out);
}